// Round 7
// baseline (442.197 us; speedup 1.0000x reference)
//
#include <hip/hip_runtime.h>
#include <math.h>

// Problem constants (from reference)
#define NQ 32768   // query points (pos1)
#define MC 8192    // source points (pos2)
#define CC 128     // channels
#define EPS_BN 1e-5f
#define EPS_D  1e-8

#define DBL_BIG 1e300
#define IDX_BIG 0x7fffffff

// KNN config
#define QB  64          // queries per block (1 per lane)
#define TB  512         // threads per block (8 waves)
#define NW  8           // waves per block
#define CH  2048        // candidates staged per chunk
#define HM  (MC / 2)    // half of M per block = 4096
#define NCH (HM / CH)   // 2 chunks per block
#define SLC (CH / NW)   // per-chunk per-wave slice = 256
#define KMASK 0xFFFFE000u   // keep sign+exp+10 mantissa bits
#define IMASK 0x1FFFu       // 13-bit index (M=8192)
#define NSURV 64            // survivors per query (2 halves x 8 waves x 4)
#define KNN_B ((NQ / QB) * 2)   // 1024 scan blocks
#define GEMM_B (NQ / 64)        // 512

typedef __attribute__((ext_vector_type(8))) short bf16x8;   // 8 bf16 (4 VGPRs)
typedef __attribute__((ext_vector_type(4))) float floatx4;  // MFMA accumulator
typedef unsigned short ushort_t;

__device__ __forceinline__ unsigned umin_(unsigned a, unsigned b) { return a < b ? a : b; }
__device__ __forceinline__ unsigned umax_(unsigned a, unsigned b) { return a > b ? a : b; }

// RNE fp32 -> bf16 pair packed in u32 (lo = a, hi = b)
__device__ __forceinline__ unsigned bf16pair(float a, float b) {
    unsigned ua = __float_as_uint(a); ua = (ua + 0x7FFFu + ((ua >> 16) & 1u)) >> 16;
    unsigned ub = __float_as_uint(b); ub = (ub + 0x7FFFu + ((ub >> 16) & 1u)) >> 16;
    return ua | (ub << 16);
}

// ---------------------------------------------------------------------------
// KNN scan + (piggy-backed) weight conversion + counter init.
// Blocks [0, KNN_B): 64 queries x half of M; 8 waves each scan 512 cands.
//   LDS stages (x,y,z,|p2|^2); d = fma(m2x,x,fma(m2y,y,fma(m2z,z,s2+s1)))
//   (4 VALU; expansion-form error ~1e-6 absorbed by top-4 + fp64 re-rank).
//   Sortable key = (bits(d) & KMASK) | idx; branchless 7-op min/max ladder.
// Blocks [KNN_B, KNN_B+8): convert W0/W1/W2 fp32 -> bf16; block KNN_B also
//   zeroes the last-block counters (runs before any gemm -> visible).
// ---------------------------------------------------------------------------
__global__ __launch_bounds__(TB) void knn_kernel(const float* __restrict__ pos1,
                                                 const float* __restrict__ pos2,
                                                 unsigned* __restrict__ skeys,
                                                 const float* __restrict__ W0,
                                                 const float* __restrict__ W1,
                                                 const float* __restrict__ W2,
                                                 ushort_t* __restrict__ Wbf,
                                                 unsigned* __restrict__ cnt) {
    __shared__ __align__(16) float4 sp4[CH];   // 32 KB: x,y,z,|p|^2
    __shared__ unsigned skey[QB][NW * 4];      // 8 KB survivor keys

    if (blockIdx.x >= KNN_B) {                 // ---- prep blocks ----
        const int pb = blockIdx.x - KNN_B;     // 0..7
        const int f = pb * TB + threadIdx.x;   // float4 index within a layer
        const float* Ws[3] = {W0, W1, W2};
#pragma unroll
        for (int l = 0; l < 3; ++l) {
            const float4 v = ((const float4*)Ws[l])[f];
            unsigned* dst = (unsigned*)(Wbf + (size_t)l * CC * CC);
            dst[f * 2 + 0] = bf16pair(v.x, v.y);
            dst[f * 2 + 1] = bf16pair(v.z, v.w);
        }
        if (pb == 0 && threadIdx.x < 4) cnt[threadIdx.x] = 0u;
        return;
    }

    const int half = blockIdx.x & 1;
    const int bq   = blockIdx.x >> 1;
    const int wv = threadIdx.x >> 6;   // wave 0..7
    const int ln = threadIdx.x & 63;   // lane = query owner
    const int q  = bq * QB + ln;

    const float px = pos1[q * 3 + 0];
    const float py = pos1[q * 3 + 1];
    const float pz = pos1[q * 3 + 2];
    const float s1 = px * px + py * py + pz * pz;
    const float m2x = -2.f * px, m2y = -2.f * py, m2z = -2.f * pz;

    unsigned k0 = 0xFFFFFFFFu, k1 = 0xFFFFFFFFu, k2 = 0xFFFFFFFFu, k3 = 0xFFFFFFFFu;

    for (int c0 = 0; c0 < NCH; ++c0) {
        const int cb = half * HM + c0 * CH;
        __syncthreads();
        {   // stage 4 candidates per thread: 3 contiguous float4 loads
            const float4* g = (const float4*)(pos2 + (size_t)(cb + threadIdx.x * 4) * 3);
            const float4 f0 = g[0], f1 = g[1], f2 = g[2];
            sp4[threadIdx.x * 4 + 0] = make_float4(f0.x, f0.y, f0.z,
                fmaf(f0.x, f0.x, fmaf(f0.y, f0.y, f0.z * f0.z)));
            sp4[threadIdx.x * 4 + 1] = make_float4(f0.w, f1.x, f1.y,
                fmaf(f0.w, f0.w, fmaf(f1.x, f1.x, f1.y * f1.y)));
            sp4[threadIdx.x * 4 + 2] = make_float4(f1.z, f1.w, f2.x,
                fmaf(f1.z, f1.z, fmaf(f1.w, f1.w, f2.x * f2.x)));
            sp4[threadIdx.x * 4 + 3] = make_float4(f2.y, f2.z, f2.w,
                fmaf(f2.y, f2.y, fmaf(f2.z, f2.z, f2.w * f2.w)));
        }
        __syncthreads();
        const float4* b4 = sp4 + wv * SLC;
        const int jb = cb + wv * SLC;
#pragma unroll 4
        for (int e = 0; e < SLC; ++e) {
            const float4 c = b4[e];   // wave-uniform address -> LDS broadcast
            const float d = fmaf(m2x, c.x, fmaf(m2y, c.y, fmaf(m2z, c.z, c.w + s1)));
            unsigned ek = (__float_as_uint(d) & KMASK) | (unsigned)(jb + e);
            unsigned t;
            t = umin_(k0, ek); ek = umax_(k0, ek); k0 = t;
            t = umin_(k1, ek); ek = umax_(k1, ek); k1 = t;
            t = umin_(k2, ek); ek = umax_(k2, ek); k2 = t;
            k3 = umin_(k3, ek);
        }
    }
    skey[ln][wv * 4 + 0] = k0;
    skey[ln][wv * 4 + 1] = k1;
    skey[ln][wv * 4 + 2] = k2;
    skey[ln][wv * 4 + 3] = k3;
    __syncthreads();

    // coalesced dump: query q's survivors at skeys[q*64 + half*32 + slot]
#pragma unroll
    for (int t = threadIdx.x * 4; t < threadIdx.x * 4 + 4; ++t) {
        const int ql = t >> 5, slot = t & 31;
        skeys[(size_t)(bq * QB + ql) * NSURV + half * 32 + slot] = skey[ql][slot];
    }
}

// ---------------------------------------------------------------------------
// bf16-MFMA fused layer GEMM: Y = Xin @ W^T + bias (fp32 accumulate).
//   MODE 0: prologue re-ranks this block's own 64 queries (fp64 exact, index
//           tie-break) from skeys, then Xin = interp(feat2, idx, w).
//   MODE 1: Xin = relu(Xsrc * scaleIn[c] + shiftIn[c]).
// Epilogue: bias, Y store, column sum/ssq -> agent-scope partials store;
// LAST block (ACQ_REL counter) reduces partials -> BN scale/shift for the
// next layer (read by the next kernel; kernel boundary flushes).
// grid = 512, block = 256.
// ---------------------------------------------------------------------------
template <int MODE>
__global__ __launch_bounds__(256) void gemm_mfma(const float* __restrict__ Xsrc,
                                                 const unsigned* __restrict__ skeys,
                                                 const float* __restrict__ pos1,
                                                 const float* __restrict__ pos2,
                                                 const float* __restrict__ scaleIn,
                                                 const float* __restrict__ shiftIn,
                                                 const ushort_t* __restrict__ Wb,
                                                 const float* __restrict__ bias,
                                                 const float* __restrict__ g,
                                                 const float* __restrict__ be,
                                                 float* __restrict__ Y,
                                                 float* __restrict__ partials,
                                                 unsigned* __restrict__ cnt,
                                                 float* __restrict__ scOut,
                                                 float* __restrict__ shOut) {
    __shared__ __align__(16) short xa[64][136];    // 64 rows x 128 k bf16
    __shared__ __align__(16) short wb[128][136];   // 128 co x 128 k bf16
    __shared__ float blk_s[CC], blk_q[CC];
    __shared__ int lastFlag;

    const int row0 = blockIdx.x * 64;

    // ---- X tile staging (+ fused transform) ----
    if constexpr (MODE == 0) {
        __shared__ int   lidx[QB][3];
        __shared__ float lw[QB][3];
        {   // exact fp64 re-rank of this block's 64 queries; 4 thr/query
            double* rrd = (double*)&xa[0][0];   // [64][4][3] = 6144 B
            int*    rri = (int*)&wb[0][0];      // [64][4][3] = 3072 B
            const int ql = threadIdx.x >> 2;
            const int pp = threadIdx.x & 3;
            const int qg = row0 + ql;
            const double qx = (double)pos1[qg * 3 + 0];
            const double qy = (double)pos1[qg * 3 + 1];
            const double qz = (double)pos1[qg * 3 + 2];
            double b0 = DBL_BIG, b1 = DBL_BIG, b2 = DBL_BIG;
            int    j0 = IDX_BIG, j1 = IDX_BIG, j2 = IDX_BIG;
            const uint4* kp = (const uint4*)(skeys + (size_t)qg * NSURV + pp * 16);
#pragma unroll
            for (int gi = 0; gi < 4; ++gi) {
                const uint4 kk = kp[gi];
                const unsigned ks[4] = {kk.x, kk.y, kk.z, kk.w};
#pragma unroll
                for (int u = 0; u < 4; ++u) {
                    const int id = (int)(ks[u] & IMASK);
                    const double x = (double)pos2[id * 3 + 0];
                    const double y = (double)pos2[id * 3 + 1];
                    const double z = (double)pos2[id * 3 + 2];
                    const double ax = qx - x, ay = qy - y, az = qz - z;
                    const double d = ax * ax + ay * ay + az * az;
                    const bool l2 = (d < b2) || (d == b2 && id < j2);
                    if (l2) {
                        const bool l1 = (d < b1) || (d == b1 && id < j1);
                        const bool l0 = (d < b0) || (d == b0 && id < j0);
                        b2 = l1 ? b1 : d;              j2 = l1 ? j1 : id;
                        b1 = l1 ? (l0 ? b0 : d) : b1;  j1 = l1 ? (l0 ? j0 : id) : j1;
                        b0 = l0 ? d : b0;              j0 = l0 ? id : j0;
                    }
                }
            }
            const int base = (ql * 4 + pp) * 3;
            rrd[base + 0] = b0; rri[base + 0] = j0;
            rrd[base + 1] = b1; rri[base + 1] = j1;
            rrd[base + 2] = b2; rri[base + 2] = j2;
            __syncthreads();
            if (threadIdx.x < QB) {
                const int qq = threadIdx.x;
                double c0 = DBL_BIG, c1 = DBL_BIG, c2 = DBL_BIG;
                int    i0 = IDX_BIG, i1 = IDX_BIG, i2 = IDX_BIG;
#pragma unroll
                for (int s = 0; s < 12; ++s) {
                    const double d = rrd[qq * 12 + s];
                    const int   id = rri[qq * 12 + s];
                    const bool l2 = (d < c2) || (d == c2 && id < i2);
                    if (l2) {
                        const bool l1 = (d < c1) || (d == c1 && id < i1);
                        const bool l0 = (d < c0) || (d == c0 && id < i0);
                        c2 = l1 ? c1 : d;              i2 = l1 ? i1 : id;
                        c1 = l1 ? (l0 ? c0 : d) : c1;  i1 = l1 ? (l0 ? i0 : id) : i1;
                        c0 = l0 ? d : c0;              i0 = l0 ? id : i0;
                    }
                }
                const double r0 = 1.0 / (c0 + EPS_D);
                const double r1 = 1.0 / (c1 + EPS_D);
                const double r2 = 1.0 / (c2 + EPS_D);
                const double inv = 1.0 / (r0 + r1 + r2);
                lidx[qq][0] = i0; lidx[qq][1] = i1; lidx[qq][2] = i2;
                lw[qq][0] = (float)(r0 * inv);
                lw[qq][1] = (float)(r1 * inv);
                lw[qq][2] = (float)(r2 * inv);
            }
            __syncthreads();
        }
        if (threadIdx.x < CC) { blk_s[threadIdx.x] = 0.f; blk_q[threadIdx.x] = 0.f; }
#pragma unroll
        for (int e = threadIdx.x; e < 64 * 32; e += 256) {
            const int r = e >> 5, c4 = e & 31;
            const int i0 = lidx[r][0], i1 = lidx[r][1], i2 = lidx[r][2];
            const float w0 = lw[r][0], w1 = lw[r][1], w2 = lw[r][2];
            const float4 f0 = *(const float4*)&Xsrc[(size_t)i0 * CC + c4 * 4];
            const float4 f1 = *(const float4*)&Xsrc[(size_t)i1 * CC + c4 * 4];
            const float4 f2 = *(const float4*)&Xsrc[(size_t)i2 * CC + c4 * 4];
            float4 v;
            v.x = w0 * f0.x + w1 * f1.x + w2 * f2.x;
            v.y = w0 * f0.y + w1 * f1.y + w2 * f2.y;
            v.z = w0 * f0.z + w1 * f1.z + w2 * f2.z;
            v.w = w0 * f0.w + w1 * f1.w + w2 * f2.w;
            unsigned* dst = (unsigned*)&xa[r][0];
            dst[c4 * 2 + 0] = bf16pair(v.x, v.y);
            dst[c4 * 2 + 1] = bf16pair(v.z, v.w);
        }
    } else {
        if (threadIdx.x < CC) { blk_s[threadIdx.x] = 0.f; blk_q[threadIdx.x] = 0.f; }
#pragma unroll
        for (int e = threadIdx.x; e < 64 * 32; e += 256) {
            const int r = e >> 5, c4 = e & 31;
            const float4 x  = *(const float4*)&Xsrc[(size_t)(row0 + r) * CC + c4 * 4];
            const float4 sc = *(const float4*)&scaleIn[c4 * 4];
            const float4 sh = *(const float4*)&shiftIn[c4 * 4];
            float4 v;
            v.x = fmaxf(fmaf(x.x, sc.x, sh.x), 0.f);
            v.y = fmaxf(fmaf(x.y, sc.y, sh.y), 0.f);
            v.z = fmaxf(fmaf(x.z, sc.z, sh.z), 0.f);
            v.w = fmaxf(fmaf(x.w, sc.w, sh.w), 0.f);
            unsigned* dst = (unsigned*)&xa[r][0];
            dst[c4 * 2 + 0] = bf16pair(v.x, v.y);
            dst[c4 * 2 + 1] = bf16pair(v.z, v.w);
        }
    }
    // ---- W tile staging: pre-converted bf16, 16B copies ----
#pragma unroll
    for (int e = threadIdx.x; e < 128 * 16; e += 256) {
        const int co = e >> 4, seg = e & 15;
        *(float4*)&wb[co][seg * 8] = *(const float4*)&Wb[(size_t)co * CC + seg * 8];
    }
    __syncthreads();

    const int lane = threadIdx.x & 63;
    const int wv = threadIdx.x >> 6;     // wave -> rows 16*wv..+15
    const int nn = lane & 15;
    const int quad = lane >> 4;

    floatx4 acc[8] = {};

    const short* arow = &xa[wv * 16 + nn][0];
#pragma unroll
    for (int ks = 0; ks < 4; ++ks) {
        const bf16x8 a = *(const bf16x8*)(arow + ks * 32 + quad * 8);
#pragma unroll
        for (int ct = 0; ct < 8; ++ct) {
            const bf16x8 b = *(const bf16x8*)(&wb[ct * 16 + nn][0] + ks * 32 + quad * 8);
            acc[ct] = __builtin_amdgcn_mfma_f32_16x16x32_bf16(a, b, acc[ct], 0, 0, 0);
        }
    }

    // ---- epilogue: bias, Y store, column stats ----
#pragma unroll
    for (int ct = 0; ct < 8; ++ct) {
        const float bv = bias[ct * 16 + nn];
        float s = 0.f, qv = 0.f;
#pragma unroll
        for (int r = 0; r < 4; ++r) {
            acc[ct][r] += bv;
            s += acc[ct][r];
            qv = fmaf(acc[ct][r], acc[ct][r], qv);
        }
#pragma unroll
        for (int r = 0; r < 4; ++r)
            Y[(size_t)(row0 + wv * 16 + quad * 4 + r) * CC + ct * 16 + nn] = acc[ct][r];
        s += __shfl_xor(s, 16, 64); s += __shfl_xor(s, 32, 64);
        qv += __shfl_xor(qv, 16, 64); qv += __shfl_xor(qv, 32, 64);
        if (quad == 0) {
            atomicAdd(&blk_s[ct * 16 + nn], s);
            atomicAdd(&blk_q[ct * 16 + nn], qv);
        }
    }
    __syncthreads();
    // publish partials (agent-scope: device-coherent across XCDs)
    {
        const int ch = threadIdx.x;
        const float v = (ch < CC) ? blk_s[ch] : blk_q[ch - CC];
        __hip_atomic_store(&partials[(size_t)ch * GEMM_B + blockIdx.x], v,
                           __ATOMIC_RELAXED, __HIP_MEMORY_SCOPE_AGENT);
    }
    __syncthreads();   // drains vmcnt: all 256 partial stores complete
    if (threadIdx.x == 0) {
        const unsigned old = __hip_atomic_fetch_add(cnt, 1u, __ATOMIC_ACQ_REL,
                                                    __HIP_MEMORY_SCOPE_AGENT);
        lastFlag = (old == (unsigned)(gridDim.x - 1)) ? 1 : 0;
    }
    __syncthreads();
    if (lastFlag) {   // last block reduces partials -> scale/shift
        const int t = threadIdx.x;   // ch-row: 0..127 sum, 128..255 ssq
        float tot = 0.f;
        const float* row = partials + (size_t)t * GEMM_B;
#pragma unroll 8
        for (int i = 0; i < GEMM_B; ++i)
            tot += __hip_atomic_load(&row[i], __ATOMIC_RELAXED, __HIP_MEMORY_SCOPE_AGENT);
        if (t < CC) blk_s[t] = tot; else blk_q[t - CC] = tot;
        __syncthreads();
        if (t < CC) {
            const float m = blk_s[t] * (1.f / (float)NQ);
            const float v = fmaf(-m, m, blk_q[t] * (1.f / (float)NQ));
            const float rstd = rsqrtf(v + EPS_BN);
            const float scl = g[t] * rstd;
            scOut[t] = scl;                    // plain store: next kernel reads
            shOut[t] = fmaf(-m, scl, be[t]);   // (kernel boundary flushes)
        }
    }
}

// ---------------------------------------------------------------------------
// Final BN + ReLU (vectorized float4). grid = NQ*CC/1024.
// ---------------------------------------------------------------------------
__global__ __launch_bounds__(256) void bn_relu_kernel(const float* __restrict__ Y,
                                                      const float* __restrict__ sc,
                                                      const float* __restrict__ sh,
                                                      float* __restrict__ out) {
    const int i4 = blockIdx.x * 256 + threadIdx.x;
    const int c4 = (i4 & 31) * 4;
    const float4 y = ((const float4*)Y)[i4];
    const float4 s = *(const float4*)&sc[c4];
    const float4 h = *(const float4*)&sh[c4];
    float4 o;
    o.x = fmaxf(fmaf(y.x, s.x, h.x), 0.f);
    o.y = fmaxf(fmaf(y.y, s.y, h.y), 0.f);
    o.z = fmaxf(fmaf(y.z, s.z, h.z), 0.f);
    o.w = fmaxf(fmaf(y.w, s.w, h.w), 0.f);
    ((float4*)out)[i4] = o;
}

// ---------------------------------------------------------------------------
extern "C" void kernel_launch(void* const* d_in, const int* in_sizes, int n_in,
                              void* d_out, int out_size, void* d_ws, size_t ws_size,
                              hipStream_t stream) {
    (void)in_sizes; (void)n_in; (void)out_size; (void)ws_size;

    const float* pos1  = (const float*)d_in[0];
    const float* pos2  = (const float*)d_in[1];
    const float* feat2 = (const float*)d_in[2];
    const float* Wl[3]  = {(const float*)d_in[3], (const float*)d_in[7],  (const float*)d_in[11]};
    const float* bl[3]  = {(const float*)d_in[4], (const float*)d_in[8],  (const float*)d_in[12]};
    const float* gl[3]  = {(const float*)d_in[5], (const float*)d_in[9],  (const float*)d_in[13]};
    const float* bel[3] = {(const float*)d_in[6], (const float*)d_in[10], (const float*)d_in[14]};

    // Workspace layout (floats). skeys aliases B1 (consumed by gemm0 before
    // gemm1 writes B1).
    float* ws = (float*)d_ws;
    float* B0   = ws;                               // NQ*CC (16 MB)
    float* B1   = B0 + (size_t)NQ * CC;             // NQ*CC (16 MB)
    unsigned* skeys = (unsigned*)B1;                // NQ*64 u32 (8 MB, aliased)
    float* part = B1 + (size_t)NQ * CC;             // 256*512 (512 KB)
    float* scsh = part + 256 * GEMM_B;              // 3 layers x (sc128, sh128)
    ushort_t* Wbf = (ushort_t*)(scsh + 3 * 256);    // 3*16384 bf16 (96 KB)
    unsigned* cnt = (unsigned*)(Wbf + 3 * CC * CC); // 4 counters

    float* sc0 = scsh + 0 * 256; float* sh0 = sc0 + CC;
    float* sc1 = scsh + 1 * 256; float* sh1 = sc1 + CC;
    float* sc2 = scsh + 2 * 256; float* sh2 = sc2 + CC;

    // 1: KNN scan + W bf16 prep + counter init
    knn_kernel<<<KNN_B + 8, TB, 0, stream>>>(pos1, pos2, skeys,
                                             Wl[0], Wl[1], Wl[2], Wbf, cnt);
    // 2: layer 0 (rerank + interp fused; last block -> sc0/sh0)
    gemm_mfma<0><<<GEMM_B, 256, 0, stream>>>(feat2, skeys, pos1, pos2,
                                             nullptr, nullptr,
                                             Wbf + 0 * CC * CC, bl[0], gl[0], bel[0],
                                             B0, part, cnt + 0, sc0, sh0);
    // 3: layer 1 (BN fused; overwrites skeys region B1 — already consumed)
    gemm_mfma<1><<<GEMM_B, 256, 0, stream>>>(B0, nullptr, nullptr, nullptr,
                                             sc0, sh0,
                                             Wbf + 1 * CC * CC, bl[1], gl[1], bel[1],
                                             B1, part, cnt + 1, sc1, sh1);
    // 4: layer 2
    gemm_mfma<1><<<GEMM_B, 256, 0, stream>>>(B1, nullptr, nullptr, nullptr,
                                             sc1, sh1,
                                             Wbf + 2 * CC * CC, bl[2], gl[2], bel[2],
                                             B0, part, cnt + 2, sc2, sh2);
    // 5: final BN+ReLU
    bn_relu_kernel<<<(size_t)NQ * CC / 1024, 256, 0, stream>>>(B0, sc2, sh2, (float*)d_out);
}

// Round 8
// 230.947 us; speedup vs baseline: 1.9147x; 1.9147x over previous
//
#include <hip/hip_runtime.h>
#include <math.h>

// Problem constants (from reference)
#define NQ 32768   // query points (pos1)
#define MC 8192    // source points (pos2)
#define CC 128     // channels
#define EPS_BN 1e-5f
#define EPS_D  1e-8

#define DBL_BIG 1e300
#define IDX_BIG 0x7fffffff

// KNN config
#define QB  64          // queries per block (1 per lane)
#define TB  512         // threads per block (8 waves)
#define NW  8           // waves per block
#define CH  2048        // candidates staged per chunk
#define HM  (MC / 2)    // half of M per block = 4096
#define NCH (HM / CH)   // 2 chunks per block
#define SLC (CH / NW)   // per-chunk per-wave slice = 256
#define KMASK 0xFFFFE000u   // keep sign+exp+10 mantissa bits
#define IMASK 0x1FFFu       // 13-bit index (M=8192)
#define NSURV 64            // survivors per query (2 halves x 8 waves x 4)
#define KNN_B ((NQ / QB) * 2)   // 1024 scan blocks
#define GEMM_B (NQ / 64)        // 512

typedef __attribute__((ext_vector_type(8))) short bf16x8;   // 8 bf16 (4 VGPRs)
typedef __attribute__((ext_vector_type(4))) float floatx4;  // MFMA accumulator
typedef unsigned short ushort_t;

__device__ __forceinline__ unsigned umin_(unsigned a, unsigned b) { return a < b ? a : b; }
__device__ __forceinline__ unsigned umax_(unsigned a, unsigned b) { return a > b ? a : b; }

// RNE fp32 -> bf16 pair packed in u32 (lo = a, hi = b)
__device__ __forceinline__ unsigned bf16pair(float a, float b) {
    unsigned ua = __float_as_uint(a); ua = (ua + 0x7FFFu + ((ua >> 16) & 1u)) >> 16;
    unsigned ub = __float_as_uint(b); ub = (ub + 0x7FFFu + ((ub >> 16) & 1u)) >> 16;
    return ua | (ub << 16);
}

// ---------------------------------------------------------------------------
// KNN scan + piggy-backed weight conversion.
// Blocks [0, KNN_B): 64 queries x half of M; 8 waves each scan 512 cands.
//   LDS stages (x,y,z,|p2|^2); d = s1+s2-2*dot (expansion form, const-s1
//   offset per query; error ~1e-6 absorbed by top-4 + fp64 re-rank).
//   Sortable key = (bits(d) & KMASK) | idx. GUARDED branchless ladder:
//   `if (ek < k3)` is a wave-coherent skip ~76% of iters; when entered,
//   masked lanes' ladder is a no-op, so per-lane semantics are unchanged.
// Blocks [KNN_B, KNN_B+8): convert W0/W1/W2 fp32 -> bf16.
// ---------------------------------------------------------------------------
__global__ __launch_bounds__(TB) void knn_kernel(const float* __restrict__ pos1,
                                                 const float* __restrict__ pos2,
                                                 unsigned* __restrict__ skeys,
                                                 const float* __restrict__ W0,
                                                 const float* __restrict__ W1,
                                                 const float* __restrict__ W2,
                                                 ushort_t* __restrict__ Wbf) {
    __shared__ __align__(16) float4 sp4[CH];   // 32 KB: x,y,z,|p|^2
    __shared__ unsigned skey[QB][NW * 4];      // 8 KB survivor keys

    if (blockIdx.x >= KNN_B) {                 // ---- prep blocks ----
        const int pb = blockIdx.x - KNN_B;     // 0..7
        const int f = pb * TB + threadIdx.x;   // float4 index within a layer
        const float* Ws[3] = {W0, W1, W2};
#pragma unroll
        for (int l = 0; l < 3; ++l) {
            const float4 v = ((const float4*)Ws[l])[f];
            unsigned* dst = (unsigned*)(Wbf + (size_t)l * CC * CC);
            dst[f * 2 + 0] = bf16pair(v.x, v.y);
            dst[f * 2 + 1] = bf16pair(v.z, v.w);
        }
        return;
    }

    const int half = blockIdx.x & 1;
    const int bq   = blockIdx.x >> 1;
    const int wv = threadIdx.x >> 6;   // wave 0..7
    const int ln = threadIdx.x & 63;   // lane = query owner
    const int q  = bq * QB + ln;

    const float px = pos1[q * 3 + 0];
    const float py = pos1[q * 3 + 1];
    const float pz = pos1[q * 3 + 2];
    const float s1 = px * px + py * py + pz * pz;
    const float m2x = -2.f * px, m2y = -2.f * py, m2z = -2.f * pz;

    unsigned k0 = 0xFFFFFFFFu, k1 = 0xFFFFFFFFu, k2 = 0xFFFFFFFFu, k3 = 0xFFFFFFFFu;

    for (int c0 = 0; c0 < NCH; ++c0) {
        const int cb = half * HM + c0 * CH;
        __syncthreads();
        {   // stage 4 candidates per thread: 3 contiguous float4 loads
            const float4* g = (const float4*)(pos2 + (size_t)(cb + threadIdx.x * 4) * 3);
            const float4 f0 = g[0], f1 = g[1], f2 = g[2];
            sp4[threadIdx.x * 4 + 0] = make_float4(f0.x, f0.y, f0.z,
                fmaf(f0.x, f0.x, fmaf(f0.y, f0.y, f0.z * f0.z)));
            sp4[threadIdx.x * 4 + 1] = make_float4(f0.w, f1.x, f1.y,
                fmaf(f0.w, f0.w, fmaf(f1.x, f1.x, f1.y * f1.y)));
            sp4[threadIdx.x * 4 + 2] = make_float4(f1.z, f1.w, f2.x,
                fmaf(f1.z, f1.z, fmaf(f1.w, f1.w, f2.x * f2.x)));
            sp4[threadIdx.x * 4 + 3] = make_float4(f2.y, f2.z, f2.w,
                fmaf(f2.y, f2.y, fmaf(f2.z, f2.z, f2.w * f2.w)));
        }
        __syncthreads();
        const float4* b4 = sp4 + wv * SLC;
        const int jb = cb + wv * SLC;
#pragma unroll 4
        for (int e = 0; e < SLC; ++e) {
            const float4 c = b4[e];   // wave-uniform address -> LDS broadcast
            const float d = fmaf(m2x, c.x, fmaf(m2y, c.y, fmaf(m2z, c.z, c.w + s1)));
            unsigned ek = (__float_as_uint(d) & KMASK) | (unsigned)(jb + e);
            if (ek < k3) {   // wave-coherent skip late in the scan
                unsigned t;
                t = umin_(k0, ek); ek = umax_(k0, ek); k0 = t;
                t = umin_(k1, ek); ek = umax_(k1, ek); k1 = t;
                t = umin_(k2, ek); ek = umax_(k2, ek); k2 = t;
                k3 = umin_(k3, ek);
            }
        }
    }
    skey[ln][wv * 4 + 0] = k0;
    skey[ln][wv * 4 + 1] = k1;
    skey[ln][wv * 4 + 2] = k2;
    skey[ln][wv * 4 + 3] = k3;
    __syncthreads();

    // coalesced dump: query q's survivors at skeys[q*64 + half*32 + slot]
#pragma unroll
    for (int t = threadIdx.x * 4; t < threadIdx.x * 4 + 4; ++t) {
        const int ql = t >> 5, slot = t & 31;
        skeys[(size_t)(bq * QB + ql) * NSURV + half * 32 + slot] = skey[ql][slot];
    }
}

// ---------------------------------------------------------------------------
// bf16-MFMA fused layer GEMM: Y = Xin @ W^T + bias (fp32 accumulate).
//   MODE 0: prologue re-ranks this block's own 64 queries (fp64 exact, index
//           tie-break) from skeys, then Xin = interp(feat2, idx, w).
//   MODE 1: Xin = relu(Xsrc * scaleIn[c] + shiftIn[c]).
// Epilogue: bias, Y store, column sum/ssq -> channel-major partials
// (plain stores; kernel-boundary flush gives coherence to reduce_stats).
// grid = 512, block = 256.
// ---------------------------------------------------------------------------
template <int MODE>
__global__ __launch_bounds__(256) void gemm_mfma(const float* __restrict__ Xsrc,
                                                 const unsigned* __restrict__ skeys,
                                                 const float* __restrict__ pos1,
                                                 const float* __restrict__ pos2,
                                                 const float* __restrict__ scaleIn,
                                                 const float* __restrict__ shiftIn,
                                                 const ushort_t* __restrict__ Wb,
                                                 const float* __restrict__ bias,
                                                 float* __restrict__ Y,
                                                 float* __restrict__ partials) {
    __shared__ __align__(16) short xa[64][136];    // 64 rows x 128 k bf16
    __shared__ __align__(16) short wb[128][136];   // 128 co x 128 k bf16
    __shared__ float blk_s[CC], blk_q[CC];

    const int row0 = blockIdx.x * 64;

    // ---- X tile staging (+ fused transform) ----
    if constexpr (MODE == 0) {
        __shared__ int   lidx[QB][3];
        __shared__ float lw[QB][3];
        {   // exact fp64 re-rank of this block's 64 queries; 4 thr/query
            double* rrd = (double*)&xa[0][0];   // [64][4][3] = 6144 B scratch
            int*    rri = (int*)&wb[0][0];      // [64][4][3] = 3072 B scratch
            const int ql = threadIdx.x >> 2;
            const int pp = threadIdx.x & 3;
            const int qg = row0 + ql;
            const double qx = (double)pos1[qg * 3 + 0];
            const double qy = (double)pos1[qg * 3 + 1];
            const double qz = (double)pos1[qg * 3 + 2];
            double b0 = DBL_BIG, b1 = DBL_BIG, b2 = DBL_BIG;
            int    j0 = IDX_BIG, j1 = IDX_BIG, j2 = IDX_BIG;
            const uint4* kp = (const uint4*)(skeys + (size_t)qg * NSURV + pp * 16);
#pragma unroll
            for (int gi = 0; gi < 4; ++gi) {
                const uint4 kk = kp[gi];
                const unsigned ks[4] = {kk.x, kk.y, kk.z, kk.w};
#pragma unroll
                for (int u = 0; u < 4; ++u) {
                    const int id = (int)(ks[u] & IMASK);
                    const double x = (double)pos2[id * 3 + 0];
                    const double y = (double)pos2[id * 3 + 1];
                    const double z = (double)pos2[id * 3 + 2];
                    const double ax = qx - x, ay = qy - y, az = qz - z;
                    const double d = ax * ax + ay * ay + az * az;
                    const bool l2 = (d < b2) || (d == b2 && id < j2);
                    if (l2) {
                        const bool l1 = (d < b1) || (d == b1 && id < j1);
                        const bool l0 = (d < b0) || (d == b0 && id < j0);
                        b2 = l1 ? b1 : d;              j2 = l1 ? j1 : id;
                        b1 = l1 ? (l0 ? b0 : d) : b1;  j1 = l1 ? (l0 ? j0 : id) : j1;
                        b0 = l0 ? d : b0;              j0 = l0 ? id : j0;
                    }
                }
            }
            const int base = (ql * 4 + pp) * 3;
            rrd[base + 0] = b0; rri[base + 0] = j0;
            rrd[base + 1] = b1; rri[base + 1] = j1;
            rrd[base + 2] = b2; rri[base + 2] = j2;
            __syncthreads();
            if (threadIdx.x < QB) {
                const int qq = threadIdx.x;
                double c0 = DBL_BIG, c1 = DBL_BIG, c2 = DBL_BIG;
                int    i0 = IDX_BIG, i1 = IDX_BIG, i2 = IDX_BIG;
#pragma unroll
                for (int s = 0; s < 12; ++s) {
                    const double d = rrd[qq * 12 + s];
                    const int   id = rri[qq * 12 + s];
                    const bool l2 = (d < c2) || (d == c2 && id < i2);
                    if (l2) {
                        const bool l1 = (d < c1) || (d == c1 && id < i1);
                        const bool l0 = (d < c0) || (d == c0 && id < i0);
                        c2 = l1 ? c1 : d;              i2 = l1 ? i1 : id;
                        c1 = l1 ? (l0 ? c0 : d) : c1;  i1 = l1 ? (l0 ? i0 : id) : i1;
                        c0 = l0 ? d : c0;              i0 = l0 ? id : i0;
                    }
                }
                const double r0 = 1.0 / (c0 + EPS_D);
                const double r1 = 1.0 / (c1 + EPS_D);
                const double r2 = 1.0 / (c2 + EPS_D);
                const double inv = 1.0 / (r0 + r1 + r2);
                lidx[qq][0] = i0; lidx[qq][1] = i1; lidx[qq][2] = i2;
                lw[qq][0] = (float)(r0 * inv);
                lw[qq][1] = (float)(r1 * inv);
                lw[qq][2] = (float)(r2 * inv);
            }
            __syncthreads();
        }
        if (threadIdx.x < CC) { blk_s[threadIdx.x] = 0.f; blk_q[threadIdx.x] = 0.f; }
#pragma unroll
        for (int e = threadIdx.x; e < 64 * 32; e += 256) {
            const int r = e >> 5, c4 = e & 31;
            const int i0 = lidx[r][0], i1 = lidx[r][1], i2 = lidx[r][2];
            const float w0 = lw[r][0], w1 = lw[r][1], w2 = lw[r][2];
            const float4 f0 = *(const float4*)&Xsrc[(size_t)i0 * CC + c4 * 4];
            const float4 f1 = *(const float4*)&Xsrc[(size_t)i1 * CC + c4 * 4];
            const float4 f2 = *(const float4*)&Xsrc[(size_t)i2 * CC + c4 * 4];
            float4 v;
            v.x = w0 * f0.x + w1 * f1.x + w2 * f2.x;
            v.y = w0 * f0.y + w1 * f1.y + w2 * f2.y;
            v.z = w0 * f0.z + w1 * f1.z + w2 * f2.z;
            v.w = w0 * f0.w + w1 * f1.w + w2 * f2.w;
            unsigned* dst = (unsigned*)&xa[r][0];
            dst[c4 * 2 + 0] = bf16pair(v.x, v.y);
            dst[c4 * 2 + 1] = bf16pair(v.z, v.w);
        }
    } else {
        if (threadIdx.x < CC) { blk_s[threadIdx.x] = 0.f; blk_q[threadIdx.x] = 0.f; }
#pragma unroll
        for (int e = threadIdx.x; e < 64 * 32; e += 256) {
            const int r = e >> 5, c4 = e & 31;
            const float4 x  = *(const float4*)&Xsrc[(size_t)(row0 + r) * CC + c4 * 4];
            const float4 sc = *(const float4*)&scaleIn[c4 * 4];
            const float4 sh = *(const float4*)&shiftIn[c4 * 4];
            float4 v;
            v.x = fmaxf(fmaf(x.x, sc.x, sh.x), 0.f);
            v.y = fmaxf(fmaf(x.y, sc.y, sh.y), 0.f);
            v.z = fmaxf(fmaf(x.z, sc.z, sh.z), 0.f);
            v.w = fmaxf(fmaf(x.w, sc.w, sh.w), 0.f);
            unsigned* dst = (unsigned*)&xa[r][0];
            dst[c4 * 2 + 0] = bf16pair(v.x, v.y);
            dst[c4 * 2 + 1] = bf16pair(v.z, v.w);
        }
    }
    // ---- W tile staging: pre-converted bf16, 16B copies ----
#pragma unroll
    for (int e = threadIdx.x; e < 128 * 16; e += 256) {
        const int co = e >> 4, seg = e & 15;
        *(float4*)&wb[co][seg * 8] = *(const float4*)&Wb[(size_t)co * CC + seg * 8];
    }
    __syncthreads();

    const int lane = threadIdx.x & 63;
    const int wv = threadIdx.x >> 6;     // wave -> rows 16*wv..+15
    const int nn = lane & 15;
    const int quad = lane >> 4;

    floatx4 acc[8] = {};

    const short* arow = &xa[wv * 16 + nn][0];
#pragma unroll
    for (int ks = 0; ks < 4; ++ks) {
        const bf16x8 a = *(const bf16x8*)(arow + ks * 32 + quad * 8);
#pragma unroll
        for (int ct = 0; ct < 8; ++ct) {
            const bf16x8 b = *(const bf16x8*)(&wb[ct * 16 + nn][0] + ks * 32 + quad * 8);
            acc[ct] = __builtin_amdgcn_mfma_f32_16x16x32_bf16(a, b, acc[ct], 0, 0, 0);
        }
    }

    // ---- epilogue: bias, Y store, column stats ----
#pragma unroll
    for (int ct = 0; ct < 8; ++ct) {
        const float bv = bias[ct * 16 + nn];
        float s = 0.f, qv = 0.f;
#pragma unroll
        for (int r = 0; r < 4; ++r) {
            acc[ct][r] += bv;
            s += acc[ct][r];
            qv = fmaf(acc[ct][r], acc[ct][r], qv);
        }
#pragma unroll
        for (int r = 0; r < 4; ++r)
            Y[(size_t)(row0 + wv * 16 + quad * 4 + r) * CC + ct * 16 + nn] = acc[ct][r];
        s += __shfl_xor(s, 16, 64); s += __shfl_xor(s, 32, 64);
        qv += __shfl_xor(qv, 16, 64); qv += __shfl_xor(qv, 32, 64);
        if (quad == 0) {
            atomicAdd(&blk_s[ct * 16 + nn], s);
            atomicAdd(&blk_q[ct * 16 + nn], qv);
        }
    }
    __syncthreads();
    // channel-major partials: partials[ch][block], ch 0..127 = sum, 128..255 = ssq
    {
        const int ch = threadIdx.x;
        const float v = (ch < CC) ? blk_s[ch] : blk_q[ch - CC];
        partials[(size_t)ch * GEMM_B + blockIdx.x] = v;
    }
}

// ---------------------------------------------------------------------------
// Reduce channel-major partials [256][512] -> BN scale/shift.
// grid = 128 blocks (one per channel) x 256 threads.
// ---------------------------------------------------------------------------
__global__ __launch_bounds__(256) void reduce_stats(const float* __restrict__ P,
                                                    const float* __restrict__ g,
                                                    const float* __restrict__ be,
                                                    float* __restrict__ sc,
                                                    float* __restrict__ sh) {
    __shared__ float accS[4], accQ[4];
    const int c = blockIdx.x;
    const int t = threadIdx.x;
    float s  = P[(size_t)c * GEMM_B + t]        + P[(size_t)c * GEMM_B + 256 + t];
    float qv = P[(size_t)(c + CC) * GEMM_B + t] + P[(size_t)(c + CC) * GEMM_B + 256 + t];
#pragma unroll
    for (int off = 32; off >= 1; off >>= 1) {
        s  += __shfl_xor(s, off, 64);
        qv += __shfl_xor(qv, off, 64);
    }
    if ((t & 63) == 0) { accS[t >> 6] = s; accQ[t >> 6] = qv; }
    __syncthreads();
    if (t == 0) {
        const float S = accS[0] + accS[1] + accS[2] + accS[3];
        const float Q = accQ[0] + accQ[1] + accQ[2] + accQ[3];
        const float m = S * (1.f / (float)NQ);
        const float v = fmaf(-m, m, Q * (1.f / (float)NQ));
        const float rstd = rsqrtf(v + EPS_BN);
        const float scl = g[c] * rstd;
        sc[c] = scl;
        sh[c] = fmaf(-m, scl, be[c]);
    }
}

// ---------------------------------------------------------------------------
// Final BN + ReLU (vectorized float4). grid = NQ*CC/1024.
// ---------------------------------------------------------------------------
__global__ __launch_bounds__(256) void bn_relu_kernel(const float* __restrict__ Y,
                                                      const float* __restrict__ sc,
                                                      const float* __restrict__ sh,
                                                      float* __restrict__ out) {
    const int i4 = blockIdx.x * 256 + threadIdx.x;
    const int c4 = (i4 & 31) * 4;
    const float4 y = ((const float4*)Y)[i4];
    const float4 s = *(const float4*)&sc[c4];
    const float4 h = *(const float4*)&sh[c4];
    float4 o;
    o.x = fmaxf(fmaf(y.x, s.x, h.x), 0.f);
    o.y = fmaxf(fmaf(y.y, s.y, h.y), 0.f);
    o.z = fmaxf(fmaf(y.z, s.z, h.z), 0.f);
    o.w = fmaxf(fmaf(y.w, s.w, h.w), 0.f);
    ((float4*)out)[i4] = o;
}

// ---------------------------------------------------------------------------
extern "C" void kernel_launch(void* const* d_in, const int* in_sizes, int n_in,
                              void* d_out, int out_size, void* d_ws, size_t ws_size,
                              hipStream_t stream) {
    (void)in_sizes; (void)n_in; (void)out_size; (void)ws_size;

    const float* pos1  = (const float*)d_in[0];
    const float* pos2  = (const float*)d_in[1];
    const float* feat2 = (const float*)d_in[2];
    const float* Wl[3]  = {(const float*)d_in[3], (const float*)d_in[7],  (const float*)d_in[11]};
    const float* bl[3]  = {(const float*)d_in[4], (const float*)d_in[8],  (const float*)d_in[12]};
    const float* gl[3]  = {(const float*)d_in[5], (const float*)d_in[9],  (const float*)d_in[13]};
    const float* bel[3] = {(const float*)d_in[6], (const float*)d_in[10], (const float*)d_in[14]};

    // Workspace layout (floats). skeys aliases B1 (consumed by gemm0 before
    // gemm1 writes B1).
    float* ws = (float*)d_ws;
    float* B0   = ws;                               // NQ*CC (16 MB)
    float* B1   = B0 + (size_t)NQ * CC;             // NQ*CC (16 MB)
    unsigned* skeys = (unsigned*)B1;                // NQ*64 u32 (8 MB, aliased)
    float* part = B1 + (size_t)NQ * CC;             // 256*512 (512 KB)
    float* scsh = part + 256 * GEMM_B;              // 3 layers x (sc128, sh128)
    ushort_t* Wbf = (ushort_t*)(scsh + 3 * 256);    // 3*16384 bf16 (96 KB)

    float* sc0 = scsh + 0 * 256; float* sh0 = sc0 + CC;
    float* sc1 = scsh + 1 * 256; float* sh1 = sc1 + CC;
    float* sc2 = scsh + 2 * 256; float* sh2 = sc2 + CC;

    // 1: KNN scan + W bf16 prep
    knn_kernel<<<KNN_B + 8, TB, 0, stream>>>(pos1, pos2, skeys,
                                             Wl[0], Wl[1], Wl[2], Wbf);
    // 2: layer 0 (rerank + interp fused)
    gemm_mfma<0><<<GEMM_B, 256, 0, stream>>>(feat2, skeys, pos1, pos2,
                                             nullptr, nullptr,
                                             Wbf + 0 * CC * CC, bl[0], B0, part);
    reduce_stats<<<CC, 256, 0, stream>>>(part, gl[0], bel[0], sc0, sh0);
    // 3: layer 1 (BN fused; overwrites skeys region B1 — already consumed)
    gemm_mfma<1><<<GEMM_B, 256, 0, stream>>>(B0, nullptr, nullptr, nullptr,
                                             sc0, sh0,
                                             Wbf + 1 * CC * CC, bl[1], B1, part);
    reduce_stats<<<CC, 256, 0, stream>>>(part, gl[1], bel[1], sc1, sh1);
    // 4: layer 2
    gemm_mfma<1><<<GEMM_B, 256, 0, stream>>>(B1, nullptr, nullptr, nullptr,
                                             sc1, sh1,
                                             Wbf + 2 * CC * CC, bl[2], B0, part);
    reduce_stats<<<CC, 256, 0, stream>>>(part, gl[2], bel[2], sc2, sh2);
    // 5: final BN+ReLU
    bn_relu_kernel<<<(size_t)NQ * CC / 1024, 256, 0, stream>>>(B0, sc2, sh2, (float*)d_out);
}

// Round 10
// 217.353 us; speedup vs baseline: 2.0345x; 1.0625x over previous
//
#include <hip/hip_runtime.h>
#include <math.h>

// Problem constants (from reference)
#define NQ 32768   // query points (pos1)
#define MC 8192    // source points (pos2)
#define CC 128     // channels
#define EPS_BN 1e-5f
#define EPS_D  1e-8

#define DBL_BIG 1e300
#define IDX_BIG 0x7fffffff

// KNN config (R6-proven form)
#define QB  64          // queries per block (1 per lane)
#define TB  512         // threads per block (8 waves)
#define NW  8           // waves per block
#define CH  2048        // candidates staged per chunk
#define HM  (MC / 2)    // half of M per block = 4096
#define NCH (HM / CH)   // 2 chunks per block
#define SLC (CH / NW)   // per-chunk per-wave slice = 256
#define KMASK 0xFFFFE000u   // keep sign+exp+10 mantissa bits
#define IMASK 0x1FFFu       // 13-bit index (M=8192)
#define NSURV 64            // survivors per query (2 halves x 8 waves x 4)
#define KNN_B ((NQ / QB) * 2)   // 1024 scan blocks
#define GEMM_B (NQ / 64)        // 512
#define NGRP 8                  // stats atomic groups (2048 addresses)

typedef __attribute__((ext_vector_type(8))) short bf16x8;   // 8 bf16 (4 VGPRs)
typedef __attribute__((ext_vector_type(4))) float floatx4;  // MFMA accumulator
typedef unsigned short ushort_t;

__device__ __forceinline__ unsigned umin_(unsigned a, unsigned b) { return a < b ? a : b; }
__device__ __forceinline__ unsigned umax_(unsigned a, unsigned b) { return a > b ? a : b; }

// RNE fp32 -> bf16 pair packed in u32 (lo = a, hi = b)
__device__ __forceinline__ unsigned bf16pair(float a, float b) {
    unsigned ua = __float_as_uint(a); ua = (ua + 0x7FFFu + ((ua >> 16) & 1u)) >> 16;
    unsigned ub = __float_as_uint(b); ub = (ub + 0x7FFFu + ((ub >> 16) & 1u)) >> 16;
    return ua | (ub << 16);
}

// ---------------------------------------------------------------------------
// KNN scan (R6-proven: 90.4 us) + piggy-backed weight conversion + stats zero.
// Blocks [0, KNN_B): 64 queries x half of M; 8 waves each scan 512 cands.
//   Packed 24 KB xyz staging; fp32 difference-form distance; sortable key
//   (bits(d)&KMASK)|idx; unguarded branchless 7-op min/max top-4 ladder.
// Blocks [KNN_B, KNN_B+8): convert W0/W1/W2 fp32 -> bf16 (RNE); block
//   KNN_B also zeroes the 3 layers' stats accumulators.
// ---------------------------------------------------------------------------
__global__ __launch_bounds__(TB) void knn_kernel(const float* __restrict__ pos1,
                                                 const float* __restrict__ pos2,
                                                 unsigned* __restrict__ skeys,
                                                 const float* __restrict__ W0,
                                                 const float* __restrict__ W1,
                                                 const float* __restrict__ W2,
                                                 ushort_t* __restrict__ Wbf,
                                                 float* __restrict__ stats) {
    __shared__ __align__(16) float4 sp4[CH * 3 / 4];   // 24 KB packed xyzxyz...
    __shared__ unsigned skey[QB][NW * 4];              // 8 KB survivor keys

    if (blockIdx.x >= KNN_B) {                 // ---- prep blocks ----
        const int pb = blockIdx.x - KNN_B;     // 0..7
        const int f = pb * TB + threadIdx.x;   // float4 index within a layer
        const float* Ws[3] = {W0, W1, W2};
#pragma unroll
        for (int l = 0; l < 3; ++l) {
            const float4 v = ((const float4*)Ws[l])[f];
            unsigned* dst = (unsigned*)(Wbf + (size_t)l * CC * CC);
            dst[f * 2 + 0] = bf16pair(v.x, v.y);
            dst[f * 2 + 1] = bf16pair(v.z, v.w);
        }
        if (pb == 0)
            for (int i = threadIdx.x; i < 3 * NGRP * 256; i += TB) stats[i] = 0.f;
        return;
    }

    const int half = blockIdx.x & 1;
    const int bq   = blockIdx.x >> 1;
    const int wv = threadIdx.x >> 6;   // wave 0..7
    const int ln = threadIdx.x & 63;   // lane = query owner
    const int q  = bq * QB + ln;

    const float px = pos1[q * 3 + 0];
    const float py = pos1[q * 3 + 1];
    const float pz = pos1[q * 3 + 2];

    unsigned k0 = 0xFFFFFFFFu, k1 = 0xFFFFFFFFu, k2 = 0xFFFFFFFFu, k3 = 0xFFFFFFFFu;

    for (int c0 = 0; c0 < NCH; ++c0) {
        const int cb = half * HM + c0 * CH;
        __syncthreads();
        {   // stage 24 KB chunk, coalesced float4 copy
            const float4* g4 = (const float4*)(pos2 + (size_t)cb * 3);
#pragma unroll
            for (int i = threadIdx.x; i < CH * 3 / 4; i += TB) sp4[i] = g4[i];
        }
        __syncthreads();
        const float4* b4 = sp4 + wv * (SLC * 3 / 4);
        const int jb = cb + wv * SLC;
#pragma unroll 2
        for (int gi = 0; gi < SLC / 4; ++gi) {
            const float4 A = b4[gi * 3 + 0];
            const float4 B = b4[gi * 3 + 1];
            const float4 Cv = b4[gi * 3 + 2];
            const int j = jb + gi * 4;
            const float cx[4] = {A.x, A.w, B.z, Cv.y};
            const float cy[4] = {A.y, B.x, B.w, Cv.z};
            const float cz[4] = {A.z, B.y, Cv.x, Cv.w};
#pragma unroll
            for (int u = 0; u < 4; ++u) {
                const float dx = px - cx[u], dy = py - cy[u], dz = pz - cz[u];
                const float d = fmaf(dx, dx, fmaf(dy, dy, dz * dz));
                unsigned e = (__float_as_uint(d) & KMASK) | (unsigned)(j + u);
                unsigned t;
                t = umin_(k0, e); e = umax_(k0, e); k0 = t;
                t = umin_(k1, e); e = umax_(k1, e); k1 = t;
                t = umin_(k2, e); e = umax_(k2, e); k2 = t;
                k3 = umin_(k3, e);
            }
        }
    }
    skey[ln][wv * 4 + 0] = k0;
    skey[ln][wv * 4 + 1] = k1;
    skey[ln][wv * 4 + 2] = k2;
    skey[ln][wv * 4 + 3] = k3;
    __syncthreads();

    // coalesced dump: query q's survivors at skeys[q*64 + half*32 + slot]
#pragma unroll
    for (int t = threadIdx.x * 4; t < threadIdx.x * 4 + 4; ++t) {
        const int ql = t >> 5, slot = t & 31;
        skeys[(size_t)(bq * QB + ql) * NSURV + half * 32 + slot] = skey[ql][slot];
    }
}

// ---------------------------------------------------------------------------
// bf16-MFMA fused layer GEMM: Y = Xin @ W^T + bias (fp32 accumulate).
//   MODE 0: prologue re-ranks this block's own 64 queries (fp64 exact, index
//           tie-break) from skeys, then Xin = interp(feat2, idx, w).
//   MODE 1: prologue reduces statsIn[8][256] -> BN scale/shift in LDS, then
//           Xin = relu(Xsrc * sc[c] + sh[c]).
// Epilogue: bias, Y store, column sum/ssq -> LDS reduce -> atomicAdd into
// statsOut[blockIdx&7][256] (8 groups -> low contention; zeroed by knn prep).
// grid = 512, block = 256.
// ---------------------------------------------------------------------------
template <int MODE>
__global__ __launch_bounds__(256) void gemm_mfma(const float* __restrict__ Xsrc,
                                                 const unsigned* __restrict__ skeys,
                                                 const float* __restrict__ pos1,
                                                 const float* __restrict__ pos2,
                                                 const float* __restrict__ statsIn,
                                                 const float* __restrict__ gIn,
                                                 const float* __restrict__ beIn,
                                                 const ushort_t* __restrict__ Wb,
                                                 const float* __restrict__ bias,
                                                 float* __restrict__ Y,
                                                 float* __restrict__ statsOut) {
    __shared__ __align__(16) short xa[64][136];    // 64 rows x 128 k bf16
    __shared__ __align__(16) short wb[128][136];   // 128 co x 128 k bf16
    __shared__ float blk_s[CC], blk_q[CC];         // epilogue stat accumulators
    __shared__ float sc_l[CC], sh_l[CC];           // MODE 1 BN scale/shift

    const int row0 = blockIdx.x * 64;

    // ---- X tile staging (+ fused transform) ----
    if constexpr (MODE == 0) {
        __shared__ int   lidx[QB][3];
        __shared__ float lw[QB][3];
        {   // exact fp64 re-rank of this block's 64 queries; 4 thr/query
            double* rrd = (double*)&xa[0][0];   // [64][4][3] = 6144 B scratch
            int*    rri = (int*)&wb[0][0];      // [64][4][3] = 3072 B scratch
            const int ql = threadIdx.x >> 2;
            const int pp = threadIdx.x & 3;
            const int qg = row0 + ql;
            const double qx = (double)pos1[qg * 3 + 0];
            const double qy = (double)pos1[qg * 3 + 1];
            const double qz = (double)pos1[qg * 3 + 2];
            double b0 = DBL_BIG, b1 = DBL_BIG, b2 = DBL_BIG;
            int    j0 = IDX_BIG, j1 = IDX_BIG, j2 = IDX_BIG;
            const uint4* kp = (const uint4*)(skeys + (size_t)qg * NSURV + pp * 16);
#pragma unroll
            for (int gi = 0; gi < 4; ++gi) {
                const uint4 kk = kp[gi];
                const unsigned ks[4] = {kk.x, kk.y, kk.z, kk.w};
#pragma unroll
                for (int u = 0; u < 4; ++u) {
                    const int id = (int)(ks[u] & IMASK);
                    const double x = (double)pos2[id * 3 + 0];
                    const double y = (double)pos2[id * 3 + 1];
                    const double z = (double)pos2[id * 3 + 2];
                    const double ax = qx - x, ay = qy - y, az = qz - z;
                    const double d = ax * ax + ay * ay + az * az;
                    const bool l2 = (d < b2) || (d == b2 && id < j2);
                    if (l2) {
                        const bool l1 = (d < b1) || (d == b1 && id < j1);
                        const bool l0 = (d < b0) || (d == b0 && id < j0);
                        b2 = l1 ? b1 : d;              j2 = l1 ? j1 : id;
                        b1 = l1 ? (l0 ? b0 : d) : b1;  j1 = l1 ? (l0 ? j0 : id) : j1;
                        b0 = l0 ? d : b0;              j0 = l0 ? id : j0;
                    }
                }
            }
            const int base = (ql * 4 + pp) * 3;
            rrd[base + 0] = b0; rri[base + 0] = j0;
            rrd[base + 1] = b1; rri[base + 1] = j1;
            rrd[base + 2] = b2; rri[base + 2] = j2;
            __syncthreads();
            if (threadIdx.x < QB) {
                const int qq = threadIdx.x;
                double c0 = DBL_BIG, c1 = DBL_BIG, c2 = DBL_BIG;
                int    i0 = IDX_BIG, i1 = IDX_BIG, i2 = IDX_BIG;
#pragma unroll
                for (int s = 0; s < 12; ++s) {
                    const double d = rrd[qq * 12 + s];
                    const int   id = rri[qq * 12 + s];
                    const bool l2 = (d < c2) || (d == c2 && id < i2);
                    if (l2) {
                        const bool l1 = (d < c1) || (d == c1 && id < i1);
                        const bool l0 = (d < c0) || (d == c0 && id < i0);
                        c2 = l1 ? c1 : d;              i2 = l1 ? i1 : id;
                        c1 = l1 ? (l0 ? c0 : d) : c1;  i1 = l1 ? (l0 ? i0 : id) : i1;
                        c0 = l0 ? d : c0;              i0 = l0 ? id : i0;
                    }
                }
                const double r0 = 1.0 / (c0 + EPS_D);
                const double r1 = 1.0 / (c1 + EPS_D);
                const double r2 = 1.0 / (c2 + EPS_D);
                const double inv = 1.0 / (r0 + r1 + r2);
                lidx[qq][0] = i0; lidx[qq][1] = i1; lidx[qq][2] = i2;
                lw[qq][0] = (float)(r0 * inv);
                lw[qq][1] = (float)(r1 * inv);
                lw[qq][2] = (float)(r2 * inv);
            }
            __syncthreads();
        }
        if (threadIdx.x < CC) { blk_s[threadIdx.x] = 0.f; blk_q[threadIdx.x] = 0.f; }
#pragma unroll
        for (int e = threadIdx.x; e < 64 * 32; e += 256) {
            const int r = e >> 5, c4 = e & 31;
            const int i0 = lidx[r][0], i1 = lidx[r][1], i2 = lidx[r][2];
            const float w0 = lw[r][0], w1 = lw[r][1], w2 = lw[r][2];
            const float4 f0 = *(const float4*)&Xsrc[(size_t)i0 * CC + c4 * 4];
            const float4 f1 = *(const float4*)&Xsrc[(size_t)i1 * CC + c4 * 4];
            const float4 f2 = *(const float4*)&Xsrc[(size_t)i2 * CC + c4 * 4];
            float4 v;
            v.x = w0 * f0.x + w1 * f1.x + w2 * f2.x;
            v.y = w0 * f0.y + w1 * f1.y + w2 * f2.y;
            v.z = w0 * f0.z + w1 * f1.z + w2 * f2.z;
            v.w = w0 * f0.w + w1 * f1.w + w2 * f2.w;
            unsigned* dst = (unsigned*)&xa[r][0];
            dst[c4 * 2 + 0] = bf16pair(v.x, v.y);
            dst[c4 * 2 + 1] = bf16pair(v.z, v.w);
        }
    } else {
        // ---- BN prologue: reduce 8-group stats -> scale/shift in LDS ----
        if (threadIdx.x < CC) {
            const int c = threadIdx.x;
            float s = 0.f, q = 0.f;
#pragma unroll
            for (int gr = 0; gr < NGRP; ++gr) {
                s += statsIn[gr * 256 + c];
                q += statsIn[gr * 256 + CC + c];
            }
            const float m = s * (1.f / (float)NQ);
            const float v = fmaf(-m, m, q * (1.f / (float)NQ));
            const float rstd = rsqrtf(v + EPS_BN);
            const float scl = gIn[c] * rstd;
            sc_l[c] = scl;
            sh_l[c] = fmaf(-m, scl, beIn[c]);
            blk_s[c] = 0.f; blk_q[c] = 0.f;
        }
        __syncthreads();
#pragma unroll
        for (int e = threadIdx.x; e < 64 * 32; e += 256) {
            const int r = e >> 5, c4 = e & 31;
            const float4 x  = *(const float4*)&Xsrc[(size_t)(row0 + r) * CC + c4 * 4];
            const float4 sc = *(const float4*)&sc_l[c4 * 4];
            const float4 sh = *(const float4*)&sh_l[c4 * 4];
            float4 v;
            v.x = fmaxf(fmaf(x.x, sc.x, sh.x), 0.f);
            v.y = fmaxf(fmaf(x.y, sc.y, sh.y), 0.f);
            v.z = fmaxf(fmaf(x.z, sc.z, sh.z), 0.f);
            v.w = fmaxf(fmaf(x.w, sc.w, sh.w), 0.f);
            unsigned* dst = (unsigned*)&xa[r][0];
            dst[c4 * 2 + 0] = bf16pair(v.x, v.y);
            dst[c4 * 2 + 1] = bf16pair(v.z, v.w);
        }
    }
    // ---- W tile staging: pre-converted bf16, 16B copies ----
#pragma unroll
    for (int e = threadIdx.x; e < 128 * 16; e += 256) {
        const int co = e >> 4, seg = e & 15;
        *(float4*)&wb[co][seg * 8] = *(const float4*)&Wb[(size_t)co * CC + seg * 8];
    }
    __syncthreads();

    const int lane = threadIdx.x & 63;
    const int wv = threadIdx.x >> 6;     // wave -> rows 16*wv..+15
    const int nn = lane & 15;
    const int quad = lane >> 4;

    floatx4 acc[8] = {};

    const short* arow = &xa[wv * 16 + nn][0];
#pragma unroll
    for (int ks = 0; ks < 4; ++ks) {
        const bf16x8 a = *(const bf16x8*)(arow + ks * 32 + quad * 8);
#pragma unroll
        for (int ct = 0; ct < 8; ++ct) {
            const bf16x8 b = *(const bf16x8*)(&wb[ct * 16 + nn][0] + ks * 32 + quad * 8);
            acc[ct] = __builtin_amdgcn_mfma_f32_16x16x32_bf16(a, b, acc[ct], 0, 0, 0);
        }
    }

    // ---- epilogue: bias, Y store, column stats ----
#pragma unroll
    for (int ct = 0; ct < 8; ++ct) {
        const float bv = bias[ct * 16 + nn];
        float s = 0.f, qv = 0.f;
#pragma unroll
        for (int r = 0; r < 4; ++r) {
            acc[ct][r] += bv;
            s += acc[ct][r];
            qv = fmaf(acc[ct][r], acc[ct][r], qv);
        }
#pragma unroll
        for (int r = 0; r < 4; ++r)
            Y[(size_t)(row0 + wv * 16 + quad * 4 + r) * CC + ct * 16 + nn] = acc[ct][r];
        s += __shfl_xor(s, 16, 64); s += __shfl_xor(s, 32, 64);
        qv += __shfl_xor(qv, 16, 64); qv += __shfl_xor(qv, 32, 64);
        if (quad == 0) {
            atomicAdd(&blk_s[ct * 16 + nn], s);
            atomicAdd(&blk_q[ct * 16 + nn], qv);
        }
    }
    __syncthreads();
    // 8-group global stats: low-contention atomicAdd (2048 addresses)
    {
        const int ch = threadIdx.x;
        const float v = (ch < CC) ? blk_s[ch] : blk_q[ch - CC];
        atomicAdd(&statsOut[(blockIdx.x & (NGRP - 1)) * 256 + ch], v);
    }
}

// ---------------------------------------------------------------------------
// Final BN + ReLU with in-kernel stats reduce. grid = 512 x 256;
// each block handles 64 rows (2048 float4).
// ---------------------------------------------------------------------------
__global__ __launch_bounds__(256) void bn_final(const float* __restrict__ Y,
                                                const float* __restrict__ statsIn,
                                                const float* __restrict__ g,
                                                const float* __restrict__ be,
                                                float* __restrict__ out) {
    __shared__ float sc_l[CC], sh_l[CC];
    if (threadIdx.x < CC) {
        const int c = threadIdx.x;
        float s = 0.f, q = 0.f;
#pragma unroll
        for (int gr = 0; gr < NGRP; ++gr) {
            s += statsIn[gr * 256 + c];
            q += statsIn[gr * 256 + CC + c];
        }
        const float m = s * (1.f / (float)NQ);
        const float v = fmaf(-m, m, q * (1.f / (float)NQ));
        const float rstd = rsqrtf(v + EPS_BN);
        const float scl = g[c] * rstd;
        sc_l[c] = scl;
        sh_l[c] = fmaf(-m, scl, be[c]);
    }
    __syncthreads();
    const float4* Y4 = (const float4*)Y;
    float4* O4 = (float4*)out;
    const int base = blockIdx.x * 2048 + threadIdx.x;
#pragma unroll
    for (int it = 0; it < 8; ++it) {
        const int i4 = base + it * 256;
        const int c4 = (i4 & 31) * 4;
        const float4 y = Y4[i4];
        const float4 s = *(const float4*)&sc_l[c4];
        const float4 h = *(const float4*)&sh_l[c4];
        float4 o;
        o.x = fmaxf(fmaf(y.x, s.x, h.x), 0.f);
        o.y = fmaxf(fmaf(y.y, s.y, h.y), 0.f);
        o.z = fmaxf(fmaf(y.z, s.z, h.z), 0.f);
        o.w = fmaxf(fmaf(y.w, s.w, h.w), 0.f);
        O4[i4] = o;
    }
}

// ---------------------------------------------------------------------------
extern "C" void kernel_launch(void* const* d_in, const int* in_sizes, int n_in,
                              void* d_out, int out_size, void* d_ws, size_t ws_size,
                              hipStream_t stream) {
    (void)in_sizes; (void)n_in; (void)out_size; (void)ws_size;

    const float* pos1  = (const float*)d_in[0];
    const float* pos2  = (const float*)d_in[1];
    const float* feat2 = (const float*)d_in[2];
    const float* Wl[3]  = {(const float*)d_in[3], (const float*)d_in[7],  (const float*)d_in[11]};
    const float* bl[3]  = {(const float*)d_in[4], (const float*)d_in[8],  (const float*)d_in[12]};
    const float* gl[3]  = {(const float*)d_in[5], (const float*)d_in[9],  (const float*)d_in[13]};
    const float* bel[3] = {(const float*)d_in[6], (const float*)d_in[10], (const float*)d_in[14]};

    // Workspace layout (floats). skeys aliases B1 (consumed by gemm0 before
    // gemm1 writes B1).
    float* ws = (float*)d_ws;
    float* B0   = ws;                               // NQ*CC (16 MB)
    float* B1   = B0 + (size_t)NQ * CC;             // NQ*CC (16 MB)
    unsigned* skeys = (unsigned*)B1;                // NQ*64 u32 (8 MB, aliased)
    float* stats = B1 + (size_t)NQ * CC;            // 3 * NGRP * 256 floats
    ushort_t* Wbf = (ushort_t*)(stats + 3 * NGRP * 256);   // 3*16384 bf16

    float* st0 = stats + 0 * NGRP * 256;
    float* st1 = stats + 1 * NGRP * 256;
    float* st2 = stats + 2 * NGRP * 256;

    // 1: KNN scan + W bf16 prep + stats zero
    knn_kernel<<<KNN_B + 8, TB, 0, stream>>>(pos1, pos2, skeys,
                                             Wl[0], Wl[1], Wl[2], Wbf, stats);
    // 2: layer 0 (rerank + interp fused) -> B0, st0
    gemm_mfma<0><<<GEMM_B, 256, 0, stream>>>(feat2, skeys, pos1, pos2,
                                             nullptr, nullptr, nullptr,
                                             Wbf + 0 * CC * CC, bl[0], B0, st0);
    // 3: layer 1 (stats-reduce + BN fused) -> B1 (overwrites skeys; consumed)
    gemm_mfma<1><<<GEMM_B, 256, 0, stream>>>(B0, nullptr, nullptr, nullptr,
                                             st0, gl[0], bel[0],
                                             Wbf + 1 * CC * CC, bl[1], B1, st1);
    // 4: layer 2 -> B0
    gemm_mfma<1><<<GEMM_B, 256, 0, stream>>>(B1, nullptr, nullptr, nullptr,
                                             st1, gl[1], bel[1],
                                             Wbf + 2 * CC * CC, bl[2], B0, st2);
    // 5: final BN+ReLU (stats-reduce fused) -> out
    bn_final<<<GEMM_B, 256, 0, stream>>>(B0, st2, gl[2], bel[2], (float*)d_out);
}

// Round 11
// 204.620 us; speedup vs baseline: 2.1611x; 1.0622x over previous
//
#include <hip/hip_runtime.h>
#include <math.h>

// Problem constants (from reference)
#define NQ 32768   // query points (pos1)
#define MC 8192    // source points (pos2)
#define CC 128     // channels
#define EPS_BN 1e-5f
#define EPS_D  1e-8

#define DBL_BIG 1e300
#define IDX_BIG 0x7fffffff

// KNN config (R6-proven layout)
#define QB  64          // queries per block (1 per lane)
#define TB  512         // threads per block (8 waves)
#define NW  8           // waves per block
#define CH  2048        // candidates staged per chunk
#define HM  (MC / 2)    // half of M per block = 4096
#define NCH (HM / CH)   // 2 chunks per block
#define SLC (CH / NW)   // per-chunk per-wave slice = 256
#define KMASK 0xFFFFE000u   // keep sign+exp+10 mantissa bits
#define IMASK 0x1FFFu       // 13-bit index (M=8192)
#define NSURV 64            // survivors per query (2 halves x 8 waves x 4)
#define KNN_B ((NQ / QB) * 2)   // 1024 scan blocks
#define GEMM_B (NQ / 64)        // 512
#define NGRP 8                  // stats atomic groups (2048 addresses)

typedef __attribute__((ext_vector_type(8))) short bf16x8;   // 8 bf16 (4 VGPRs)
typedef __attribute__((ext_vector_type(4))) float floatx4;  // MFMA accumulator
typedef unsigned short ushort_t;

__device__ __forceinline__ unsigned umin_(unsigned a, unsigned b) { return a < b ? a : b; }
__device__ __forceinline__ unsigned umax_(unsigned a, unsigned b) { return a > b ? a : b; }
#define KSWAP(a, b) { unsigned t_ = umin_(a, b); b = umax_(a, b); a = t_; }

// RNE fp32 -> bf16 pair packed in u32 (lo = a, hi = b)
__device__ __forceinline__ unsigned bf16pair(float a, float b) {
    unsigned ua = __float_as_uint(a); ua = (ua + 0x7FFFu + ((ua >> 16) & 1u)) >> 16;
    unsigned ub = __float_as_uint(b); ub = (ub + 0x7FFFu + ((ub >> 16) & 1u)) >> 16;
    return ua | (ub << 16);
}
__device__ __forceinline__ ushort_t bf16one(float a) {
    unsigned ua = __float_as_uint(a);
    return (ushort_t)((ua + 0x7FFFu + ((ua >> 16) & 1u)) >> 16);
}
// unpack u32 = (lo bf16, hi bf16) -> 2 fp32
__device__ __forceinline__ float bflo(unsigned u) { return __uint_as_float(u << 16); }
__device__ __forceinline__ float bfhi(unsigned u) { return __uint_as_float(u & 0xFFFF0000u); }

// ---------------------------------------------------------------------------
// KNN scan + piggy-backed weight conversion + stats zero.
// Blocks [0, KNN_B): 64 queries x half of M; 8 waves each scan 512 cands.
//   Packed 24 KB xyz staging; fp32 difference-form distance; sortable key
//   (bits(d)&KMASK)|idx. Top-4 via BATCHED BITONIC MERGE: sort the 4 new
//   keys (5 comparators), lower-half vs sorted k0..k3 (4 mins), re-sort
//   bitonic result (4 comparators) -> 22 ops/4 cands vs 28 for the ladder.
// Blocks [KNN_B, KNN_B+8): convert W0/W1/W2 fp32 -> bf16; block KNN_B also
//   zeroes the 3 layers' stats accumulators.
// ---------------------------------------------------------------------------
__global__ __launch_bounds__(TB) void knn_kernel(const float* __restrict__ pos1,
                                                 const float* __restrict__ pos2,
                                                 unsigned* __restrict__ skeys,
                                                 const float* __restrict__ W0,
                                                 const float* __restrict__ W1,
                                                 const float* __restrict__ W2,
                                                 ushort_t* __restrict__ Wbf,
                                                 float* __restrict__ stats) {
    __shared__ __align__(16) float4 sp4[CH * 3 / 4];   // 24 KB packed xyzxyz...
    __shared__ unsigned skey[QB][NW * 4];              // 8 KB survivor keys

    if (blockIdx.x >= KNN_B) {                 // ---- prep blocks ----
        const int pb = blockIdx.x - KNN_B;     // 0..7
        const int f = pb * TB + threadIdx.x;   // float4 index within a layer
        const float* Ws[3] = {W0, W1, W2};
#pragma unroll
        for (int l = 0; l < 3; ++l) {
            const float4 v = ((const float4*)Ws[l])[f];
            unsigned* dst = (unsigned*)(Wbf + (size_t)l * CC * CC);
            dst[f * 2 + 0] = bf16pair(v.x, v.y);
            dst[f * 2 + 1] = bf16pair(v.z, v.w);
        }
        if (pb == 0)
            for (int i = threadIdx.x; i < 3 * NGRP * 256; i += TB) stats[i] = 0.f;
        return;
    }

    const int half = blockIdx.x & 1;
    const int bq   = blockIdx.x >> 1;
    const int wv = threadIdx.x >> 6;   // wave 0..7
    const int ln = threadIdx.x & 63;   // lane = query owner
    const int q  = bq * QB + ln;

    const float px = pos1[q * 3 + 0];
    const float py = pos1[q * 3 + 1];
    const float pz = pos1[q * 3 + 2];

    unsigned k0 = 0xFFFFFFFFu, k1 = 0xFFFFFFFFu, k2 = 0xFFFFFFFFu, k3 = 0xFFFFFFFFu;

    for (int c0 = 0; c0 < NCH; ++c0) {
        const int cb = half * HM + c0 * CH;
        __syncthreads();
        {   // stage 24 KB chunk, coalesced float4 copy
            const float4* g4 = (const float4*)(pos2 + (size_t)cb * 3);
#pragma unroll
            for (int i = threadIdx.x; i < CH * 3 / 4; i += TB) sp4[i] = g4[i];
        }
        __syncthreads();
        const float4* b4 = sp4 + wv * (SLC * 3 / 4);
        const int jb = cb + wv * SLC;
#pragma unroll 4
        for (int gi = 0; gi < SLC / 4; ++gi) {
            const float4 A = b4[gi * 3 + 0];
            const float4 B = b4[gi * 3 + 1];
            const float4 Cv = b4[gi * 3 + 2];
            const int j = jb + gi * 4;
            const float cx[4] = {A.x, A.w, B.z, Cv.y};
            const float cy[4] = {A.y, B.x, B.w, Cv.z};
            const float cz[4] = {A.z, B.y, Cv.x, Cv.w};
            unsigned e0, e1, e2, e3;
            {
                float dx = px - cx[0], dy = py - cy[0], dz = pz - cz[0];
                e0 = (__float_as_uint(fmaf(dx, dx, fmaf(dy, dy, dz * dz))) & KMASK) | (unsigned)(j + 0);
                dx = px - cx[1]; dy = py - cy[1]; dz = pz - cz[1];
                e1 = (__float_as_uint(fmaf(dx, dx, fmaf(dy, dy, dz * dz))) & KMASK) | (unsigned)(j + 1);
                dx = px - cx[2]; dy = py - cy[2]; dz = pz - cz[2];
                e2 = (__float_as_uint(fmaf(dx, dx, fmaf(dy, dy, dz * dz))) & KMASK) | (unsigned)(j + 2);
                dx = px - cx[3]; dy = py - cy[3]; dz = pz - cz[3];
                e3 = (__float_as_uint(fmaf(dx, dx, fmaf(dy, dy, dz * dz))) & KMASK) | (unsigned)(j + 3);
            }
            // sort e0..e3 ascending (5 comparators)
            KSWAP(e0, e1); KSWAP(e2, e3); KSWAP(e0, e2); KSWAP(e1, e3); KSWAP(e1, e2);
            // bitonic lower-half of (k asc ++ e desc)
            unsigned m0 = umin_(k0, e3), m1 = umin_(k1, e2);
            unsigned m2 = umin_(k2, e1), m3 = umin_(k3, e0);
            // sort the bitonic 4 (half-cleaner + final)
            KSWAP(m0, m2); KSWAP(m1, m3); KSWAP(m0, m1); KSWAP(m2, m3);
            k0 = m0; k1 = m1; k2 = m2; k3 = m3;
        }
    }
    skey[ln][wv * 4 + 0] = k0;
    skey[ln][wv * 4 + 1] = k1;
    skey[ln][wv * 4 + 2] = k2;
    skey[ln][wv * 4 + 3] = k3;
    __syncthreads();

    // coalesced dump: query q's survivors at skeys[q*64 + half*32 + slot]
#pragma unroll
    for (int t = threadIdx.x * 4; t < threadIdx.x * 4 + 4; ++t) {
        const int ql = t >> 5, slot = t & 31;
        skeys[(size_t)(bq * QB + ql) * NSURV + half * 32 + slot] = skey[ql][slot];
    }
}

// ---------------------------------------------------------------------------
// bf16-MFMA fused layer GEMM: Y = Xin @ W^T + bias (fp32 accumulate).
//   MODE 0: prologue re-ranks this block's own 64 queries (fp64 exact) from
//           skeys, then Xin = interp(feat2(fp32), idx, w). Y out: bf16.
//   MODE 1: prologue reduces statsIn[8][256] -> BN scale/shift in LDS, then
//           Xin = relu(Xbf16 * sc[c] + sh[c]). Y out: bf16.
// Y is stored bf16 (halves inter-layer HBM traffic; next stage re-rounds to
// bf16 anyway, extra error ~2e-3/layer). Stats stay fp32 from accumulators.
// Epilogue stats -> 8-group atomicAdd (2048 addresses, zeroed by knn prep).
// grid = 512, block = 256.
// ---------------------------------------------------------------------------
template <int MODE>
__global__ __launch_bounds__(256) void gemm_mfma(const void* __restrict__ Xsrc_,
                                                 const unsigned* __restrict__ skeys,
                                                 const float* __restrict__ pos1,
                                                 const float* __restrict__ pos2,
                                                 const float* __restrict__ statsIn,
                                                 const float* __restrict__ gIn,
                                                 const float* __restrict__ beIn,
                                                 const ushort_t* __restrict__ Wb,
                                                 const float* __restrict__ bias,
                                                 ushort_t* __restrict__ Y,
                                                 float* __restrict__ statsOut) {
    __shared__ __align__(16) short xa[64][136];    // 64 rows x 128 k bf16
    __shared__ __align__(16) short wb[128][136];   // 128 co x 128 k bf16
    __shared__ float blk_s[CC], blk_q[CC];         // epilogue stat accumulators
    __shared__ float sc_l[CC], sh_l[CC];           // MODE 1 BN scale/shift

    const int row0 = blockIdx.x * 64;

    // ---- X tile staging (+ fused transform) ----
    if constexpr (MODE == 0) {
        const float* feat2 = (const float*)Xsrc_;
        __shared__ int   lidx[QB][3];
        __shared__ float lw[QB][3];
        {   // exact fp64 re-rank of this block's 64 queries; 4 thr/query
            double* rrd = (double*)&xa[0][0];   // [64][4][3] = 6144 B scratch
            int*    rri = (int*)&wb[0][0];      // [64][4][3] = 3072 B scratch
            const int ql = threadIdx.x >> 2;
            const int pp = threadIdx.x & 3;
            const int qg = row0 + ql;
            const double qx = (double)pos1[qg * 3 + 0];
            const double qy = (double)pos1[qg * 3 + 1];
            const double qz = (double)pos1[qg * 3 + 2];
            double b0 = DBL_BIG, b1 = DBL_BIG, b2 = DBL_BIG;
            int    j0 = IDX_BIG, j1 = IDX_BIG, j2 = IDX_BIG;
            const uint4* kp = (const uint4*)(skeys + (size_t)qg * NSURV + pp * 16);
#pragma unroll
            for (int gi = 0; gi < 4; ++gi) {
                const uint4 kk = kp[gi];
                const unsigned ks[4] = {kk.x, kk.y, kk.z, kk.w};
#pragma unroll
                for (int u = 0; u < 4; ++u) {
                    const int id = (int)(ks[u] & IMASK);
                    const double x = (double)pos2[id * 3 + 0];
                    const double y = (double)pos2[id * 3 + 1];
                    const double z = (double)pos2[id * 3 + 2];
                    const double ax = qx - x, ay = qy - y, az = qz - z;
                    const double d = ax * ax + ay * ay + az * az;
                    const bool l2 = (d < b2) || (d == b2 && id < j2);
                    if (l2) {
                        const bool l1 = (d < b1) || (d == b1 && id < j1);
                        const bool l0 = (d < b0) || (d == b0 && id < j0);
                        b2 = l1 ? b1 : d;              j2 = l1 ? j1 : id;
                        b1 = l1 ? (l0 ? b0 : d) : b1;  j1 = l1 ? (l0 ? j0 : id) : j1;
                        b0 = l0 ? d : b0;              j0 = l0 ? id : j0;
                    }
                }
            }
            const int base = (ql * 4 + pp) * 3;
            rrd[base + 0] = b0; rri[base + 0] = j0;
            rrd[base + 1] = b1; rri[base + 1] = j1;
            rrd[base + 2] = b2; rri[base + 2] = j2;
            __syncthreads();
            if (threadIdx.x < QB) {
                const int qq = threadIdx.x;
                double c0 = DBL_BIG, c1 = DBL_BIG, c2 = DBL_BIG;
                int    i0 = IDX_BIG, i1 = IDX_BIG, i2 = IDX_BIG;
#pragma unroll
                for (int s = 0; s < 12; ++s) {
                    const double d = rrd[qq * 12 + s];
                    const int   id = rri[qq * 12 + s];
                    const bool l2 = (d < c2) || (d == c2 && id < i2);
                    if (l2) {
                        const bool l1 = (d < c1) || (d == c1 && id < i1);
                        const bool l0 = (d < c0) || (d == c0 && id < i0);
                        c2 = l1 ? c1 : d;              i2 = l1 ? i1 : id;
                        c1 = l1 ? (l0 ? c0 : d) : c1;  i1 = l1 ? (l0 ? i0 : id) : i1;
                        c0 = l0 ? d : c0;              i0 = l0 ? id : i0;
                    }
                }
                const double r0 = 1.0 / (c0 + EPS_D);
                const double r1 = 1.0 / (c1 + EPS_D);
                const double r2 = 1.0 / (c2 + EPS_D);
                const double inv = 1.0 / (r0 + r1 + r2);
                lidx[qq][0] = i0; lidx[qq][1] = i1; lidx[qq][2] = i2;
                lw[qq][0] = (float)(r0 * inv);
                lw[qq][1] = (float)(r1 * inv);
                lw[qq][2] = (float)(r2 * inv);
            }
            __syncthreads();
        }
        if (threadIdx.x < CC) { blk_s[threadIdx.x] = 0.f; blk_q[threadIdx.x] = 0.f; }
#pragma unroll
        for (int e = threadIdx.x; e < 64 * 32; e += 256) {
            const int r = e >> 5, c4 = e & 31;
            const int i0 = lidx[r][0], i1 = lidx[r][1], i2 = lidx[r][2];
            const float w0 = lw[r][0], w1 = lw[r][1], w2 = lw[r][2];
            const float4 f0 = *(const float4*)&feat2[(size_t)i0 * CC + c4 * 4];
            const float4 f1 = *(const float4*)&feat2[(size_t)i1 * CC + c4 * 4];
            const float4 f2 = *(const float4*)&feat2[(size_t)i2 * CC + c4 * 4];
            float4 v;
            v.x = w0 * f0.x + w1 * f1.x + w2 * f2.x;
            v.y = w0 * f0.y + w1 * f1.y + w2 * f2.y;
            v.z = w0 * f0.z + w1 * f1.z + w2 * f2.z;
            v.w = w0 * f0.w + w1 * f1.w + w2 * f2.w;
            unsigned* dst = (unsigned*)&xa[r][0];
            dst[c4 * 2 + 0] = bf16pair(v.x, v.y);
            dst[c4 * 2 + 1] = bf16pair(v.z, v.w);
        }
    } else {
        const ushort_t* Xbf = (const ushort_t*)Xsrc_;
        // ---- BN prologue: reduce 8-group stats -> scale/shift in LDS ----
        if (threadIdx.x < CC) {
            const int c = threadIdx.x;
            float s = 0.f, q = 0.f;
#pragma unroll
            for (int gr = 0; gr < NGRP; ++gr) {
                s += statsIn[gr * 256 + c];
                q += statsIn[gr * 256 + CC + c];
            }
            const float m = s * (1.f / (float)NQ);
            const float v = fmaf(-m, m, q * (1.f / (float)NQ));
            const float rstd = rsqrtf(v + EPS_BN);
            const float scl = gIn[c] * rstd;
            sc_l[c] = scl;
            sh_l[c] = fmaf(-m, scl, beIn[c]);
            blk_s[c] = 0.f; blk_q[c] = 0.f;
        }
        __syncthreads();
        // X staging: uint4 = 8 bf16 per iter, 4 iters/thread
#pragma unroll
        for (int e = threadIdx.x; e < 64 * 16; e += 256) {
            const int r = e >> 4, c8 = e & 15;
            const uint4 u = *(const uint4*)&Xbf[(size_t)(row0 + r) * CC + c8 * 8];
            const float4 s0 = *(const float4*)&sc_l[c8 * 8];
            const float4 s1 = *(const float4*)&sc_l[c8 * 8 + 4];
            const float4 h0 = *(const float4*)&sh_l[c8 * 8];
            const float4 h1 = *(const float4*)&sh_l[c8 * 8 + 4];
            const float v0 = fmaxf(fmaf(bflo(u.x), s0.x, h0.x), 0.f);
            const float v1 = fmaxf(fmaf(bfhi(u.x), s0.y, h0.y), 0.f);
            const float v2 = fmaxf(fmaf(bflo(u.y), s0.z, h0.z), 0.f);
            const float v3 = fmaxf(fmaf(bfhi(u.y), s0.w, h0.w), 0.f);
            const float v4 = fmaxf(fmaf(bflo(u.z), s1.x, h1.x), 0.f);
            const float v5 = fmaxf(fmaf(bfhi(u.z), s1.y, h1.y), 0.f);
            const float v6 = fmaxf(fmaf(bflo(u.w), s1.z, h1.z), 0.f);
            const float v7 = fmaxf(fmaf(bfhi(u.w), s1.w, h1.w), 0.f);
            uint4 o;
            o.x = bf16pair(v0, v1); o.y = bf16pair(v2, v3);
            o.z = bf16pair(v4, v5); o.w = bf16pair(v6, v7);
            *(uint4*)&xa[r][c8 * 8] = o;
        }
    }
    // ---- W tile staging: pre-converted bf16, 16B copies ----
#pragma unroll
    for (int e = threadIdx.x; e < 128 * 16; e += 256) {
        const int co = e >> 4, seg = e & 15;
        *(float4*)&wb[co][seg * 8] = *(const float4*)&Wb[(size_t)co * CC + seg * 8];
    }
    __syncthreads();

    const int lane = threadIdx.x & 63;
    const int wv = threadIdx.x >> 6;     // wave -> rows 16*wv..+15
    const int nn = lane & 15;
    const int quad = lane >> 4;

    floatx4 acc[8] = {};

    const short* arow = &xa[wv * 16 + nn][0];
#pragma unroll
    for (int ks = 0; ks < 4; ++ks) {
        const bf16x8 a = *(const bf16x8*)(arow + ks * 32 + quad * 8);
#pragma unroll
        for (int ct = 0; ct < 8; ++ct) {
            const bf16x8 b = *(const bf16x8*)(&wb[ct * 16 + nn][0] + ks * 32 + quad * 8);
            acc[ct] = __builtin_amdgcn_mfma_f32_16x16x32_bf16(a, b, acc[ct], 0, 0, 0);
        }
    }

    // ---- epilogue: bias, bf16 Y store, column stats (fp32) ----
#pragma unroll
    for (int ct = 0; ct < 8; ++ct) {
        const float bv = bias[ct * 16 + nn];
        float s = 0.f, qv = 0.f;
#pragma unroll
        for (int r = 0; r < 4; ++r) {
            acc[ct][r] += bv;
            s += acc[ct][r];
            qv = fmaf(acc[ct][r], acc[ct][r], qv);
        }
#pragma unroll
        for (int r = 0; r < 4; ++r)
            Y[(size_t)(row0 + wv * 16 + quad * 4 + r) * CC + ct * 16 + nn] = bf16one(acc[ct][r]);
        s += __shfl_xor(s, 16, 64); s += __shfl_xor(s, 32, 64);
        qv += __shfl_xor(qv, 16, 64); qv += __shfl_xor(qv, 32, 64);
        if (quad == 0) {
            atomicAdd(&blk_s[ct * 16 + nn], s);
            atomicAdd(&blk_q[ct * 16 + nn], qv);
        }
    }
    __syncthreads();
    // 8-group global stats: low-contention atomicAdd (2048 addresses)
    {
        const int ch = threadIdx.x;
        const float v = (ch < CC) ? blk_s[ch] : blk_q[ch - CC];
        atomicAdd(&statsOut[(blockIdx.x & (NGRP - 1)) * 256 + ch], v);
    }
}

// ---------------------------------------------------------------------------
// Final BN + ReLU with in-kernel stats reduce; bf16 in, fp32 out.
// grid = 512 x 256; each thread handles 4 x 8 elements.
// ---------------------------------------------------------------------------
__global__ __launch_bounds__(256) void bn_final(const ushort_t* __restrict__ Y,
                                                const float* __restrict__ statsIn,
                                                const float* __restrict__ g,
                                                const float* __restrict__ be,
                                                float* __restrict__ out) {
    __shared__ float sc_l[CC], sh_l[CC];
    if (threadIdx.x < CC) {
        const int c = threadIdx.x;
        float s = 0.f, q = 0.f;
#pragma unroll
        for (int gr = 0; gr < NGRP; ++gr) {
            s += statsIn[gr * 256 + c];
            q += statsIn[gr * 256 + CC + c];
        }
        const float m = s * (1.f / (float)NQ);
        const float v = fmaf(-m, m, q * (1.f / (float)NQ));
        const float rstd = rsqrtf(v + EPS_BN);
        const float scl = g[c] * rstd;
        sc_l[c] = scl;
        sh_l[c] = fmaf(-m, scl, be[c]);
    }
    __syncthreads();
    const int base = blockIdx.x * 1024 + threadIdx.x;   // 8-col group index
#pragma unroll
    for (int it = 0; it < 4; ++it) {
        const int i8 = base + it * 256;
        const int c8 = (i8 & 15) * 8;
        const uint4 u = *(const uint4*)&Y[(size_t)i8 * 8];
        const float4 s0 = *(const float4*)&sc_l[c8];
        const float4 s1 = *(const float4*)&sc_l[c8 + 4];
        const float4 h0 = *(const float4*)&sh_l[c8];
        const float4 h1 = *(const float4*)&sh_l[c8 + 4];
        float4 o0, o1;
        o0.x = fmaxf(fmaf(bflo(u.x), s0.x, h0.x), 0.f);
        o0.y = fmaxf(fmaf(bfhi(u.x), s0.y, h0.y), 0.f);
        o0.z = fmaxf(fmaf(bflo(u.y), s0.z, h0.z), 0.f);
        o0.w = fmaxf(fmaf(bfhi(u.y), s0.w, h0.w), 0.f);
        o1.x = fmaxf(fmaf(bflo(u.z), s1.x, h1.x), 0.f);
        o1.y = fmaxf(fmaf(bfhi(u.z), s1.y, h1.y), 0.f);
        o1.z = fmaxf(fmaf(bflo(u.w), s1.z, h1.z), 0.f);
        o1.w = fmaxf(fmaf(bfhi(u.w), s1.w, h1.w), 0.f);
        ((float4*)out)[i8 * 2 + 0] = o0;
        ((float4*)out)[i8 * 2 + 1] = o1;
    }
}

// ---------------------------------------------------------------------------
extern "C" void kernel_launch(void* const* d_in, const int* in_sizes, int n_in,
                              void* d_out, int out_size, void* d_ws, size_t ws_size,
                              hipStream_t stream) {
    (void)in_sizes; (void)n_in; (void)out_size; (void)ws_size;

    const float* pos1  = (const float*)d_in[0];
    const float* pos2  = (const float*)d_in[1];
    const float* feat2 = (const float*)d_in[2];
    const float* Wl[3]  = {(const float*)d_in[3], (const float*)d_in[7],  (const float*)d_in[11]};
    const float* bl[3]  = {(const float*)d_in[4], (const float*)d_in[8],  (const float*)d_in[12]};
    const float* gl[3]  = {(const float*)d_in[5], (const float*)d_in[9],  (const float*)d_in[13]};
    const float* bel[3] = {(const float*)d_in[6], (const float*)d_in[10], (const float*)d_in[14]};

    // Workspace layout
    float* ws = (float*)d_ws;
    ushort_t* B0 = (ushort_t*)ws;                   // NQ*CC bf16 (8 MB)
    ushort_t* B1 = B0 + (size_t)NQ * CC;            // NQ*CC bf16 (8 MB)
    unsigned* skeys = (unsigned*)(B1 + (size_t)NQ * CC);   // NQ*64 u32 (8 MB)
    float* stats = (float*)(skeys + (size_t)NQ * NSURV);   // 3*NGRP*256 floats
    ushort_t* Wbf = (ushort_t*)(stats + 3 * NGRP * 256);   // 3*16384 bf16

    float* st0 = stats + 0 * NGRP * 256;
    float* st1 = stats + 1 * NGRP * 256;
    float* st2 = stats + 2 * NGRP * 256;

    // 1: KNN scan + W bf16 prep + stats zero
    knn_kernel<<<KNN_B + 8, TB, 0, stream>>>(pos1, pos2, skeys,
                                             Wl[0], Wl[1], Wl[2], Wbf, stats);
    // 2: layer 0 (rerank + interp fused) -> B0 (bf16), st0
    gemm_mfma<0><<<GEMM_B, 256, 0, stream>>>(feat2, skeys, pos1, pos2,
                                             nullptr, nullptr, nullptr,
                                             Wbf + 0 * CC * CC, bl[0], B0, st0);
    // 3: layer 1 (stats-reduce + BN fused) -> B1 (bf16), st1
    gemm_mfma<1><<<GEMM_B, 256, 0, stream>>>(B0, nullptr, nullptr, nullptr,
                                             st0, gl[0], bel[0],
                                             Wbf + 1 * CC * CC, bl[1], B1, st1);
    // 4: layer 2 -> B0 (bf16), st2
    gemm_mfma<1><<<GEMM_B, 256, 0, stream>>>(B1, nullptr, nullptr, nullptr,
                                             st1, gl[1], bel[1],
                                             Wbf + 2 * CC * CC, bl[2], B0, st2);
    // 5: final BN+ReLU (stats-reduce fused) -> out (fp32)
    bn_final<<<GEMM_B, 256, 0, stream>>>(B0, st2, gl[2], bel[2], (float*)d_out);
}